// Round 1
// baseline (516.581 us; speedup 1.0000x reference)
//
#include <hip/hip_runtime.h>
#include <hip/hip_bf16.h>
#include <cstdint>

// Problem constants
#define B_ 4
#define T_ 1024
#define W_ 33
#define F_ 512
#define H_ 8
#define DK_ 64

typedef __attribute__((ext_vector_type(8))) short short8;
typedef __attribute__((ext_vector_type(4))) float f32x4;

__device__ __forceinline__ float b2f(ushort u) {
  return __uint_as_float(((uint32_t)u) << 16);
}
__device__ __forceinline__ ushort f2b(float f) {
  union { __hip_bfloat16 b; ushort u; } cv;
  cv.b = __float2bfloat16(f);
  return cv.u;
}

// ---------------------------------------------------------------------------
// Weight convert + transpose: W[k][n] f32 -> Wt[n][k] bf16  (512x512 each)
// ---------------------------------------------------------------------------
__global__ void convert_w(const float* __restrict__ Wq, const float* __restrict__ Wk,
                          const float* __restrict__ Wv, const float* __restrict__ Wo,
                          ushort* __restrict__ out)
{
  int which = blockIdx.y;
  const float* src = (which == 0) ? Wq : (which == 1) ? Wk : (which == 2) ? Wv : Wo;
  ushort* dst = out + (size_t)which * 262144;
  int idx = blockIdx.x * 256 + threadIdx.x;     // 0 .. 262143
  int k = idx >> 9;
  int n = idx & 511;
  dst[n * 512 + k] = f2b(src[idx]);
}

// ---------------------------------------------------------------------------
// GEMM: C[M x 512] = A[M x 512] * W[512 x 512] + bias, via Wt[n][k] bf16.
// BM=128, BN=128, BK=64. 256 threads = 4 waves (2x2), wave tile 64x64.
// A is f32 (converted to bf16 during staging) or bf16. Out f32 or bf16.
// LDS tiles [row][k] bf16 with byte-offset XOR swizzle ^((row&7)<<4).
// Block swizzle: the 4 N-sibling blocks of one M-tile land on the same XCD
// (S%8 selects XCD under round-robin dispatch) so the A-tile is read from
// HBM once and reused via that XCD's L2.
// ---------------------------------------------------------------------------
template<bool A_F32, bool OUT_F32>
__global__ __launch_bounds__(256, 2)
void gemm_kernel(const void* __restrict__ Ap, const ushort* __restrict__ Bt,
                 const float* __restrict__ bias, void* __restrict__ Cp, int swz)
{
  __shared__ ushort lA[128 * 64];   // 16 KB
  __shared__ ushort lB[128 * 64];   // 16 KB

  const int tid  = threadIdx.x;
  const int lane = tid & 63;
  const int wid  = tid >> 6;
  const int wr   = wid >> 1, wc = wid & 1;
  const int lrow = lane & 15;
  const int lk8  = (lane >> 4) * 8;

  int S = blockIdx.x;
  int bm, bn;
  if (swz) { int x = S & 7; int j = S >> 3; bm = x + ((j >> 2) << 3); bn = j & 3; }
  else     { bm = S >> 2; bn = S & 3; }

  f32x4 acc[4][4];
#pragma unroll
  for (int i = 0; i < 4; ++i)
#pragma unroll
    for (int j = 0; j < 4; ++j) acc[i][j] = {0.f, 0.f, 0.f, 0.f};

  for (int ks = 0; ks < 8; ++ks) {
    // ---- stage A and B tiles into LDS (swizzled) ----
#pragma unroll
    for (int p = 0; p < 4; ++p) {
      int c   = p * 256 + tid;        // chunk of 8 bf16
      int row = c >> 3;               // tile row 0..127
      int kc  = (c & 7) * 8;          // k offset 0..56
      int lb  = (row * 128 + kc * 2) ^ ((row & 7) << 4);
      short8 hv;
      if (A_F32) {
        const float* src = (const float*)Ap + (size_t)(bm * 128 + row) * 512 + ks * 64 + kc;
        float4 u0 = *(const float4*)src;
        float4 u1 = *(const float4*)(src + 4);
        hv[0] = (short)f2b(u0.x); hv[1] = (short)f2b(u0.y);
        hv[2] = (short)f2b(u0.z); hv[3] = (short)f2b(u0.w);
        hv[4] = (short)f2b(u1.x); hv[5] = (short)f2b(u1.y);
        hv[6] = (short)f2b(u1.z); hv[7] = (short)f2b(u1.w);
      } else {
        const ushort* src = (const ushort*)Ap + (size_t)(bm * 128 + row) * 512 + ks * 64 + kc;
        hv = *(const short8*)src;
      }
      *(short8*)((char*)lA + lb) = hv;

      const ushort* bsrc = Bt + (size_t)(bn * 128 + row) * 512 + ks * 64 + kc;
      *(short8*)((char*)lB + lb) = *(const short8*)bsrc;
    }
    __syncthreads();

    // ---- compute: 2 k-slices x 4x4 fragments ----
#pragma unroll
    for (int kk = 0; kk < 2; ++kk) {
      short8 af[4], bg[4];
#pragma unroll
      for (int mf = 0; mf < 4; ++mf) {
        int row = wr * 64 + mf * 16 + lrow;
        int off = (row * 128 + (kk * 32 + lk8) * 2) ^ ((row & 7) << 4);
        af[mf] = *(const short8*)((const char*)lA + off);
      }
#pragma unroll
      for (int nf = 0; nf < 4; ++nf) {
        int row = wc * 64 + nf * 16 + lrow;
        int off = (row * 128 + (kk * 32 + lk8) * 2) ^ ((row & 7) << 4);
        bg[nf] = *(const short8*)((const char*)lB + off);
      }
#pragma unroll
      for (int mf = 0; mf < 4; ++mf)
#pragma unroll
        for (int nf = 0; nf < 4; ++nf)
          acc[mf][nf] = __builtin_amdgcn_mfma_f32_16x16x32_bf16(af[mf], bg[nf], acc[mf][nf], 0, 0, 0);
    }
    __syncthreads();
  }

  // ---- epilogue: bias + store ----
  float bs[4];
#pragma unroll
  for (int nf = 0; nf < 4; ++nf)
    bs[nf] = bias[bn * 128 + wc * 64 + nf * 16 + lrow];

  const int r0 = (lane >> 4) * 4;
#pragma unroll
  for (int mf = 0; mf < 4; ++mf) {
#pragma unroll
    for (int nf = 0; nf < 4; ++nf) {
      int gcol = bn * 128 + wc * 64 + nf * 16 + lrow;
#pragma unroll
      for (int r = 0; r < 4; ++r) {
        int grow = bm * 128 + wr * 64 + mf * 16 + r0 + r;
        float val = acc[mf][nf][r] + bs[nf];
        if (OUT_F32) ((float*)Cp)[(size_t)grow * 512 + gcol] = val;
        else         ((ushort*)Cp)[(size_t)grow * 512 + gcol] = f2b(val);
      }
    }
  }
}

// ---------------------------------------------------------------------------
// Attention: one block per (b,t). k/v rows for this t staged in LDS.
// scores[h][w] = q[h]·k[w,h]/8 ; masked softmax over w ; x[h][d] = sum_w a*v.
// Memory-bound: ~70 KB global traffic per block.
// ---------------------------------------------------------------------------
__global__ __launch_bounds__(256, 2)
void attn_kernel(const ushort* __restrict__ q, const ushort* __restrict__ k,
                 const ushort* __restrict__ v, const int* __restrict__ mask,
                 ushort* __restrict__ x, int bt0)
{
  __shared__ ushort lk[W_][520];
  __shared__ ushort lv[W_][520];
  __shared__ ushort lq[512];
  __shared__ float  sc[H_][W_];
  __shared__ float  aw[H_][W_];
  __shared__ float  mx[H_], inv[H_];
  __shared__ int    msk[W_];

  const int tid = threadIdx.x;
  const int bt  = blockIdx.x + bt0;        // global b*T + t

  // load q row (512 bf16)
  if (tid < 64) ((short8*)lq)[tid] = ((const short8*)(q + (size_t)bt * 512))[tid];
  if (tid < W_) msk[tid] = mask[(size_t)bt * W_ + tid];

  // load k,v rows for this (b,t): 33 x 512 bf16 each
  size_t kvbase = (size_t)blockIdx.x * (W_ * 512);
  for (int c = tid; c < W_ * 64; c += 256) {
    int w  = c >> 6;
    int d8 = (c & 63) * 8;
    *(short8*)&lk[w][d8] = *(const short8*)(k + kvbase + w * 512 + d8);
    *(short8*)&lv[w][d8] = *(const short8*)(v + kvbase + w * 512 + d8);
  }
  __syncthreads();

  // scores
  for (int task = tid; task < H_ * W_; task += 256) {
    int h = task / W_, w = task % W_;
    const ushort* kr = &lk[w][h * 64];
    const ushort* qr = &lq[h * 64];
    float s = 0.f;
#pragma unroll
    for (int d8 = 0; d8 < 8; ++d8) {
      short8 qv = *(const short8*)(qr + d8 * 8);
      short8 kv = *(const short8*)(kr + d8 * 8);
#pragma unroll
      for (int j = 0; j < 8; ++j) s += b2f((ushort)qv[j]) * b2f((ushort)kv[j]);
    }
    s *= 0.125f;
    sc[h][w] = msk[w] ? s : -3.4028234663852886e38f;
  }
  __syncthreads();

  // per-head max & sum
  if (tid < H_) {
    float m = -3.4028234663852886e38f;
    for (int w = 0; w < W_; ++w) m = fmaxf(m, sc[tid][w]);
    float ssum = 0.f;
    for (int w = 0; w < W_; ++w) ssum += __expf(sc[tid][w] - m);
    mx[tid] = m;
    inv[tid] = 1.f / ssum;
  }
  __syncthreads();

  for (int task = tid; task < H_ * W_; task += 256) {
    int h = task / W_, w = task % W_;
    aw[h][w] = msk[w] ? __expf(sc[h][w] - mx[h]) * inv[h] : 0.f;
  }
  __syncthreads();

  // PV: 512 outputs
  for (int f = tid; f < 512; f += 256) {
    int h = f >> 6, d = f & 63;
    float a = 0.f;
#pragma unroll
    for (int w = 0; w < W_; ++w) a += aw[h][w] * b2f(lv[w][h * 64 + d]);
    x[(size_t)bt * 512 + f] = f2b(a);
  }
}

// ---------------------------------------------------------------------------
extern "C" void kernel_launch(void* const* d_in, const int* in_sizes, int n_in,
                              void* d_out, int out_size, void* d_ws, size_t ws_size,
                              hipStream_t stream)
{
  const float* query = (const float*)d_in[0];
  const float* key   = (const float*)d_in[1];
  const float* value = (const float*)d_in[2];
  const int*   mask  = (const int*)d_in[3];
  const float* Wq    = (const float*)d_in[4];
  const float* bq    = (const float*)d_in[5];
  const float* Wk    = (const float*)d_in[6];
  const float* bk    = (const float*)d_in[7];
  const float* Wv    = (const float*)d_in[8];
  const float* bv    = (const float*)d_in[9];
  const float* Wo    = (const float*)d_in[10];
  const float* bo    = (const float*)d_in[11];

  char* ws = (char*)d_ws;
  ushort* Wt   = (ushort*)ws;                         // 4 x 512x512 bf16 = 2 MB
  ushort* Wtq  = Wt;
  ushort* Wtk  = Wt + 262144;
  ushort* Wtv  = Wt + 524288;
  ushort* Wto  = Wt + 786432;
  ushort* qws  = (ushort*)(ws + 2 * 1024 * 1024);     // 4 MB
  ushort* xws  = (ushort*)(ws + 6 * 1024 * 1024);     // 4 MB
  ushort* kvws = (ushort*)(ws + 10 * 1024 * 1024);

  // chunk the (b*T) dimension so k/v bf16 intermediates fit in ws
  size_t fixed = 10ull * 1024 * 1024;
  size_t avail = ws_size > fixed ? ws_size - fixed : 0;
  long trl = (long)(avail / (2ull * W_ * 512 * 2));   // t-rows that fit
  int TR = (int)(trl / 128) * 128;
  if (TR > B_ * T_) TR = B_ * T_;
  if (TR < 128) TR = 128;
  ushort* kws = kvws;
  ushort* vws = kvws + (size_t)TR * W_ * 512;

  convert_w<<<dim3(1024, 4), 256, 0, stream>>>(Wq, Wk, Wv, Wo, Wt);

  // Q projection: M=4096 -> 32 M-tiles
  gemm_kernel<true, false><<<32 * 4, 256, 0, stream>>>(query, Wtq, bq, qws, 1);

  for (int bt0 = 0; bt0 < B_ * T_; bt0 += TR) {
    int rows = B_ * T_ - bt0; if (rows > TR) rows = TR;
    int Mt = rows * W_ / 128;              // rows is a multiple of 128
    int sw = (Mt % 8 == 0) ? 1 : 0;
    const float* kptr = key   + (size_t)bt0 * W_ * 512;
    const float* vptr = value + (size_t)bt0 * W_ * 512;
    gemm_kernel<true, false><<<Mt * 4, 256, 0, stream>>>(kptr, Wtk, bk, kws, sw);
    gemm_kernel<true, false><<<Mt * 4, 256, 0, stream>>>(vptr, Wtv, bv, vws, sw);
    attn_kernel<<<rows, 256, 0, stream>>>(qws, kws, vws, mask, xws, bt0);
  }

  // output projection: x @ Wo + bo -> f32 d_out
  gemm_kernel<false, true><<<32 * 4, 256, 0, stream>>>(xws, Wto, bo, d_out, 1);
}

// Round 2
// 439.396 us; speedup vs baseline: 1.1757x; 1.1757x over previous
//
#include <hip/hip_runtime.h>
#include <hip/hip_bf16.h>
#include <cstdint>

// Problem constants
#define B_ 4
#define T_ 1024
#define W_ 33
#define F_ 512
#define H_ 8
#define DK_ 64

typedef __attribute__((ext_vector_type(8))) short short8;
typedef __attribute__((ext_vector_type(4))) float f32x4;

__device__ __forceinline__ float b2f(ushort u) {
  return __uint_as_float(((uint32_t)u) << 16);
}
__device__ __forceinline__ ushort f2b(float f) {
  union { __hip_bfloat16 b; ushort u; } cv;
  cv.b = __float2bfloat16(f);
  return cv.u;
}

// ---------------------------------------------------------------------------
// Weight convert + transpose: W[k][n] f32 -> Wt[n][k] bf16  (512x512 each)
// ---------------------------------------------------------------------------
__global__ void convert_w(const float* __restrict__ Wq, const float* __restrict__ Wk,
                          const float* __restrict__ Wv, const float* __restrict__ Wo,
                          ushort* __restrict__ out)
{
  int which = blockIdx.y;
  const float* src = (which == 0) ? Wq : (which == 1) ? Wk : (which == 2) ? Wv : Wo;
  ushort* dst = out + (size_t)which * 262144;
  int idx = blockIdx.x * 256 + threadIdx.x;     // 0 .. 262143
  int k = idx >> 9;
  int n = idx & 511;
  dst[n * 512 + k] = f2b(src[idx]);
}

// ---------------------------------------------------------------------------
// GEMM: C[M x 512] = A[M x 512] * W[512 x 512] + bias, via Wt[n][k] bf16.
// BM=128, BN=128, BK=64. 256 threads = 4 waves (2x2), wave tile 64x64.
// Pipelined (2-phase, reg-staged): per K-step
//   issue G-loads(t+1) -> regs | ds_read+MFMA(t) | ds_write regs->buf^1 | barrier
// Double-buffered LDS (64 KB/block). One barrier per K-step; HBM latency of
// tile t+1 hides under tile t's MFMAs. A is f32 (fused cvt->bf16) or bf16.
// LDS tiles [row][k] bf16 with byte-offset XOR swizzle ^((row&7)<<4) -> 0 conflicts.
// Block swizzle: 4 N-sibling blocks of one M-tile land on the same XCD so the
// A-tile is fetched from HBM once and reused via that XCD's L2.
// ---------------------------------------------------------------------------
template<bool A_F32, bool OUT_F32>
__global__ __launch_bounds__(256, 2)
void gemm_kernel(const void* __restrict__ Ap, const ushort* __restrict__ Bt,
                 const float* __restrict__ bias, void* __restrict__ Cp, int swz)
{
  __shared__ ushort lA[2][128 * 64];   // 2 x 16 KB
  __shared__ ushort lB[2][128 * 64];   // 2 x 16 KB

  const int tid  = threadIdx.x;
  const int lane = tid & 63;
  const int wid  = tid >> 6;
  const int wr   = wid >> 1, wc = wid & 1;
  const int lrow = lane & 15;
  const int lk8  = (lane >> 4) * 8;

  int S = blockIdx.x;
  int bm, bn;
  if (swz) { int x = S & 7; int j = S >> 3; bm = x + ((j >> 2) << 3); bn = j & 3; }
  else     { bm = S >> 2; bn = S & 3; }

  // per-thread staging geometry: 4 chunks of 8 bf16 for each of A,B
  int row_[4], lb_[4];
  size_t asrc_[4], bsrc_[4];
#pragma unroll
  for (int p = 0; p < 4; ++p) {
    int c   = p * 256 + tid;
    int row = c >> 3;
    int kc  = (c & 7) * 8;
    row_[p] = row;
    lb_[p]  = (row * 128 + kc * 2) ^ ((row & 7) << 4);
    asrc_[p] = (size_t)(bm * 128 + row) * 512 + kc;
    bsrc_[p] = (size_t)(bn * 128 + row) * 512 + kc;
  }

  float4 a0[4], a1[4];
  short8 areg[4], breg[4];

  auto issue = [&](int ks) {
#pragma unroll
    for (int p = 0; p < 4; ++p) {
      if (A_F32) {
        const float* src = (const float*)Ap + asrc_[p] + ks * 64;
        a0[p] = *(const float4*)src;
        a1[p] = *(const float4*)(src + 4);
      } else {
        areg[p] = *(const short8*)((const ushort*)Ap + asrc_[p] + ks * 64);
      }
      breg[p] = *(const short8*)(Bt + bsrc_[p] + ks * 64);
    }
  };
  auto lwrite = [&](int buf) {
#pragma unroll
    for (int p = 0; p < 4; ++p) {
      short8 hv;
      if (A_F32) {
        hv[0] = (short)f2b(a0[p].x); hv[1] = (short)f2b(a0[p].y);
        hv[2] = (short)f2b(a0[p].z); hv[3] = (short)f2b(a0[p].w);
        hv[4] = (short)f2b(a1[p].x); hv[5] = (short)f2b(a1[p].y);
        hv[6] = (short)f2b(a1[p].z); hv[7] = (short)f2b(a1[p].w);
      } else {
        hv = areg[p];
      }
      *(short8*)((char*)lA[buf] + lb_[p]) = hv;
      *(short8*)((char*)lB[buf] + lb_[p]) = breg[p];
    }
  };

  f32x4 acc[4][4];
#pragma unroll
  for (int i = 0; i < 4; ++i)
#pragma unroll
    for (int j = 0; j < 4; ++j) acc[i][j] = {0.f, 0.f, 0.f, 0.f};

  // prologue: tile 0 into buf 0
  issue(0);
  lwrite(0);
  __syncthreads();

  int cur = 0;
  for (int ks = 0; ks < 8; ++ks) {
    if (ks < 7) issue(ks + 1);          // G-loads in flight under compute

    // ---- compute tile ks from buf[cur] ----
#pragma unroll
    for (int kk = 0; kk < 2; ++kk) {
      short8 af[4], bg[4];
#pragma unroll
      for (int mf = 0; mf < 4; ++mf) {
        int row = wr * 64 + mf * 16 + lrow;
        int off = (row * 128 + (kk * 32 + lk8) * 2) ^ ((row & 7) << 4);
        af[mf] = *(const short8*)((const char*)lA[cur] + off);
      }
#pragma unroll
      for (int nf = 0; nf < 4; ++nf) {
        int row = wc * 64 + nf * 16 + lrow;
        int off = (row * 128 + (kk * 32 + lk8) * 2) ^ ((row & 7) << 4);
        bg[nf] = *(const short8*)((const char*)lB[cur] + off);
      }
#pragma unroll
      for (int mf = 0; mf < 4; ++mf)
#pragma unroll
        for (int nf = 0; nf < 4; ++nf)
          acc[mf][nf] = __builtin_amdgcn_mfma_f32_16x16x32_bf16(af[mf], bg[nf], acc[mf][nf], 0, 0, 0);
    }

    if (ks < 7) {
      lwrite(cur ^ 1);                  // waits vmcnt, publishes next tile
      __syncthreads();
      cur ^= 1;
    }
  }

  // ---- epilogue: bias + store ----
  float bs[4];
#pragma unroll
  for (int nf = 0; nf < 4; ++nf)
    bs[nf] = bias[bn * 128 + wc * 64 + nf * 16 + lrow];

  const int r0 = (lane >> 4) * 4;
#pragma unroll
  for (int mf = 0; mf < 4; ++mf) {
#pragma unroll
    for (int nf = 0; nf < 4; ++nf) {
      int gcol = bn * 128 + wc * 64 + nf * 16 + lrow;
#pragma unroll
      for (int r = 0; r < 4; ++r) {
        int grow = bm * 128 + wr * 64 + mf * 16 + r0 + r;
        float val = acc[mf][nf][r] + bs[nf];
        if (OUT_F32) ((float*)Cp)[(size_t)grow * 512 + gcol] = val;
        else         ((ushort*)Cp)[(size_t)grow * 512 + gcol] = f2b(val);
      }
    }
  }
}

// ---------------------------------------------------------------------------
// Attention: one block per (b,t). k/v rows for this t staged in LDS.
// scores[h][w] = q[h]·k[w,h]/8 ; masked softmax over w ; x[h][d] = sum_w a*v.
// Memory-bound: ~70 KB global traffic per block.
// ---------------------------------------------------------------------------
__global__ __launch_bounds__(256, 2)
void attn_kernel(const ushort* __restrict__ q, const ushort* __restrict__ k,
                 const ushort* __restrict__ v, const int* __restrict__ mask,
                 ushort* __restrict__ x, int bt0)
{
  __shared__ ushort lk[W_][520];
  __shared__ ushort lv[W_][520];
  __shared__ ushort lq[512];
  __shared__ float  sc[H_][W_];
  __shared__ float  aw[H_][W_];
  __shared__ float  mx[H_], inv[H_];
  __shared__ int    msk[W_];

  const int tid = threadIdx.x;
  const int bt  = blockIdx.x + bt0;        // global b*T + t

  // load q row (512 bf16)
  if (tid < 64) ((short8*)lq)[tid] = ((const short8*)(q + (size_t)bt * 512))[tid];
  if (tid < W_) msk[tid] = mask[(size_t)bt * W_ + tid];

  // load k,v rows for this (b,t): 33 x 512 bf16 each
  size_t kvbase = (size_t)blockIdx.x * (W_ * 512);
  for (int c = tid; c < W_ * 64; c += 256) {
    int w  = c >> 6;
    int d8 = (c & 63) * 8;
    *(short8*)&lk[w][d8] = *(const short8*)(k + kvbase + w * 512 + d8);
    *(short8*)&lv[w][d8] = *(const short8*)(v + kvbase + w * 512 + d8);
  }
  __syncthreads();

  // scores
  for (int task = tid; task < H_ * W_; task += 256) {
    int h = task / W_, w = task % W_;
    const ushort* kr = &lk[w][h * 64];
    const ushort* qr = &lq[h * 64];
    float s = 0.f;
#pragma unroll
    for (int d8 = 0; d8 < 8; ++d8) {
      short8 qv = *(const short8*)(qr + d8 * 8);
      short8 kv = *(const short8*)(kr + d8 * 8);
#pragma unroll
      for (int j = 0; j < 8; ++j) s += b2f((ushort)qv[j]) * b2f((ushort)kv[j]);
    }
    s *= 0.125f;
    sc[h][w] = msk[w] ? s : -3.4028234663852886e38f;
  }
  __syncthreads();

  // per-head max & sum
  if (tid < H_) {
    float m = -3.4028234663852886e38f;
    for (int w = 0; w < W_; ++w) m = fmaxf(m, sc[tid][w]);
    float ssum = 0.f;
    for (int w = 0; w < W_; ++w) ssum += __expf(sc[tid][w] - m);
    mx[tid] = m;
    inv[tid] = 1.f / ssum;
  }
  __syncthreads();

  for (int task = tid; task < H_ * W_; task += 256) {
    int h = task / W_, w = task % W_;
    aw[h][w] = msk[w] ? __expf(sc[h][w] - mx[h]) * inv[h] : 0.f;
  }
  __syncthreads();

  // PV: 512 outputs
  for (int f = tid; f < 512; f += 256) {
    int h = f >> 6, d = f & 63;
    float a = 0.f;
#pragma unroll
    for (int w = 0; w < W_; ++w) a += aw[h][w] * b2f(lv[w][h * 64 + d]);
    x[(size_t)bt * 512 + f] = f2b(a);
  }
}

// ---------------------------------------------------------------------------
extern "C" void kernel_launch(void* const* d_in, const int* in_sizes, int n_in,
                              void* d_out, int out_size, void* d_ws, size_t ws_size,
                              hipStream_t stream)
{
  const float* query = (const float*)d_in[0];
  const float* key   = (const float*)d_in[1];
  const float* value = (const float*)d_in[2];
  const int*   mask  = (const int*)d_in[3];
  const float* Wq    = (const float*)d_in[4];
  const float* bq    = (const float*)d_in[5];
  const float* Wk    = (const float*)d_in[6];
  const float* bk    = (const float*)d_in[7];
  const float* Wv    = (const float*)d_in[8];
  const float* bv    = (const float*)d_in[9];
  const float* Wo    = (const float*)d_in[10];
  const float* bo    = (const float*)d_in[11];

  char* ws = (char*)d_ws;
  ushort* Wt   = (ushort*)ws;                         // 4 x 512x512 bf16 = 2 MB
  ushort* Wtq  = Wt;
  ushort* Wtk  = Wt + 262144;
  ushort* Wtv  = Wt + 524288;
  ushort* Wto  = Wt + 786432;
  ushort* qws  = (ushort*)(ws + 2 * 1024 * 1024);     // 4 MB
  ushort* xws  = (ushort*)(ws + 6 * 1024 * 1024);     // 4 MB
  ushort* kvws = (ushort*)(ws + 10 * 1024 * 1024);

  // chunk the (b*T) dimension so k/v bf16 intermediates fit in ws
  size_t fixed = 10ull * 1024 * 1024;
  size_t avail = ws_size > fixed ? ws_size - fixed : 0;
  long trl = (long)(avail / (2ull * W_ * 512 * 2));   // t-rows that fit
  int TR = (int)(trl / 128) * 128;
  if (TR > B_ * T_) TR = B_ * T_;
  if (TR < 128) TR = 128;
  ushort* kws = kvws;
  ushort* vws = kvws + (size_t)TR * W_ * 512;

  convert_w<<<dim3(1024, 4), 256, 0, stream>>>(Wq, Wk, Wv, Wo, Wt);

  // Q projection: M=4096 -> 32 M-tiles
  gemm_kernel<true, false><<<32 * 4, 256, 0, stream>>>(query, Wtq, bq, qws, 1);

  for (int bt0 = 0; bt0 < B_ * T_; bt0 += TR) {
    int rows = B_ * T_ - bt0; if (rows > TR) rows = TR;
    int Mt = rows * W_ / 128;              // rows is a multiple of 128
    int sw = (Mt % 8 == 0) ? 1 : 0;
    const float* kptr = key   + (size_t)bt0 * W_ * 512;
    const float* vptr = value + (size_t)bt0 * W_ * 512;
    gemm_kernel<true, false><<<Mt * 4, 256, 0, stream>>>(kptr, Wtk, bk, kws, sw);
    gemm_kernel<true, false><<<Mt * 4, 256, 0, stream>>>(vptr, Wtv, bv, vws, sw);
    attn_kernel<<<rows, 256, 0, stream>>>(qws, kws, vws, mask, xws, bt0);
  }

  // output projection: x @ Wo + bo -> f32 d_out
  gemm_kernel<false, true><<<32 * 4, 256, 0, stream>>>(xws, Wto, bo, d_out, 1);
}

// Round 3
// 405.292 us; speedup vs baseline: 1.2746x; 1.0841x over previous
//
#include <hip/hip_runtime.h>
#include <hip/hip_bf16.h>
#include <cstdint>

// Problem constants
#define B_ 4
#define T_ 1024
#define W_ 33
#define F_ 512
#define H_ 8
#define DK_ 64

typedef __attribute__((ext_vector_type(8))) short short8;
typedef __attribute__((ext_vector_type(4))) float f32x4;

__device__ __forceinline__ float b2f(ushort u) {
  return __uint_as_float(((uint32_t)u) << 16);
}
__device__ __forceinline__ ushort f2b(float f) {
  union { __hip_bfloat16 b; ushort u; } cv;
  cv.b = __float2bfloat16(f);
  return cv.u;
}

// ---------------------------------------------------------------------------
// Weight convert: W[k][n] f32 -> bf16 in MFMA *fragment order*:
//   dst[((nt*16 + kc)*64 + lane)*8 + e] = W[k][n]
//   with n = nt*16 + (lane&15), k = kc*32 + (lane>>4)*8 + e.
// A wave's B-fragment load (16x16x32 MFMA, n-tile nt, k-chunk kc) is then one
// coalesced 16B/lane global_load_dwordx4 from offset ((nt*16+kc)*64+lane)*8.
// ---------------------------------------------------------------------------
__global__ void convert_w(const float* __restrict__ Wq, const float* __restrict__ Wk,
                          const float* __restrict__ Wv, const float* __restrict__ Wo,
                          ushort* __restrict__ out)
{
  int which = blockIdx.y;
  const float* src = (which == 0) ? Wq : (which == 1) ? Wk : (which == 2) ? Wv : Wo;
  ushort* dst = out + (size_t)which * 262144;
  int idx = blockIdx.x * 256 + threadIdx.x;     // 0 .. 262143
  int e  = idx & 7;
  int l  = (idx >> 3) & 63;
  int kc = (idx >> 9) & 15;
  int nt = idx >> 13;
  int k = kc * 32 + ((l >> 4) << 3) + e;
  int n = (nt << 4) + (l & 15);
  dst[idx] = f2b(src[k * 512 + n]);
}

// ---------------------------------------------------------------------------
// GEMM: C[M x 512] = A[M x 512] * W[512 x 512] + bias.
// BM=128, BN=128, BK=64. 256 threads = 4 waves (2x2), wave tile 64x64.
// A: reg-staged (fused f32->bf16 cvt) into XOR-swizzled LDS, double-buffered
//    (2x16KB only). 2-phase pipeline: issue A(t+1) | compute(t) | write A(t+1).
// B: NO LDS — fragment-ordered global layout, loaded per K-step as 8 coalesced
//    dwordx4 L2 hits straight into MFMA operand registers.
// Dual-input (blockIdx.y selects) so K-proj and V-proj share one dispatch.
// Block swizzle: 4 N-sibling blocks of one M-tile land consecutively on the
// same XCD -> A-tile fetched from HBM once, reused via that XCD's L2.
// ---------------------------------------------------------------------------
template<bool A_F32, bool OUT_F32>
__global__ __launch_bounds__(256, 3)
void gemm_kernel(const void* __restrict__ A0p, const void* __restrict__ A1p,
                 const ushort* __restrict__ B0, const ushort* __restrict__ B1,
                 const float* __restrict__ bias0, const float* __restrict__ bias1,
                 void* __restrict__ C0, void* __restrict__ C1, int swz)
{
  __shared__ ushort lA[2][128 * 64];   // 2 x 16 KB

  const int tid  = threadIdx.x;
  const int lane = tid & 63;
  const int wid  = tid >> 6;
  const int wr   = wid >> 1, wc = wid & 1;
  const int lrow = lane & 15;
  const int lk8  = (lane >> 4) * 8;

  const void* Ap; const ushort* Bf; const float* bias; void* Cp;
  if (blockIdx.y == 0) { Ap = A0p; Bf = B0; bias = bias0; Cp = C0; }
  else                 { Ap = A1p; Bf = B1; bias = bias1; Cp = C1; }

  int S = blockIdx.x;
  int bm, bn;
  if (swz) { int x = S & 7; int j = S >> 3; bm = x + ((j >> 2) << 3); bn = j & 3; }
  else     { bm = S >> 2; bn = S & 3; }

  // per-thread A staging geometry: 4 chunks of 8 bf16 (tile 128 x 64)
  int lb_[4];
  size_t asrc_[4];
#pragma unroll
  for (int p = 0; p < 4; ++p) {
    int c   = p * 256 + tid;
    int row = c >> 3;               // 0..127
    int kc  = (c & 7) * 8;          // 0..56
    lb_[p]  = (row * 128 + kc * 2) ^ ((row & 7) << 4);
    asrc_[p] = (size_t)(bm * 128 + row) * 512 + kc;
  }

  float4 a0[4], a1[4];
  short8 areg[4];

  auto issueA = [&](int ks) {
#pragma unroll
    for (int p = 0; p < 4; ++p) {
      if (A_F32) {
        const float* src = (const float*)Ap + asrc_[p] + ks * 64;
        a0[p] = *(const float4*)src;
        a1[p] = *(const float4*)(src + 4);
      } else {
        areg[p] = *(const short8*)((const ushort*)Ap + asrc_[p] + ks * 64);
      }
    }
  };
  auto lwriteA = [&](int buf) {
#pragma unroll
    for (int p = 0; p < 4; ++p) {
      short8 hv;
      if (A_F32) {
        hv[0] = (short)f2b(a0[p].x); hv[1] = (short)f2b(a0[p].y);
        hv[2] = (short)f2b(a0[p].z); hv[3] = (short)f2b(a0[p].w);
        hv[4] = (short)f2b(a1[p].x); hv[5] = (short)f2b(a1[p].y);
        hv[6] = (short)f2b(a1[p].z); hv[7] = (short)f2b(a1[p].w);
      } else {
        hv = areg[p];
      }
      *(short8*)((char*)lA[buf] + lb_[p]) = hv;
    }
  };

  const int ntb = bn * 8 + wc * 4;   // wave's base n-tile (of 32)

  f32x4 acc[4][4];
#pragma unroll
  for (int i = 0; i < 4; ++i)
#pragma unroll
    for (int j = 0; j < 4; ++j) acc[i][j] = {0.f, 0.f, 0.f, 0.f};

  issueA(0);
  lwriteA(0);
  __syncthreads();

  int cur = 0;
  for (int ks = 0; ks < 8; ++ks) {
    // B fragments for this K-step: 8 coalesced L2 loads (issued BEFORE the
    // HBM A-prefetch so their vmcnt retirement isn't queued behind it).
    short8 bfr[8];
#pragma unroll
    for (int kk = 0; kk < 2; ++kk)
#pragma unroll
      for (int nf = 0; nf < 4; ++nf)
        bfr[kk * 4 + nf] = *(const short8*)(Bf +
            (((size_t)(ntb + nf) * 16 + ks * 2 + kk) * 64 + lane) * 8);

    if (ks < 7) issueA(ks + 1);      // HBM loads in flight under compute

#pragma unroll
    for (int kk = 0; kk < 2; ++kk) {
      short8 af[4];
#pragma unroll
      for (int mf = 0; mf < 4; ++mf) {
        int row = wr * 64 + mf * 16 + lrow;
        int off = (row * 128 + (kk * 32 + lk8) * 2) ^ ((row & 7) << 4);
        af[mf] = *(const short8*)((const char*)lA[cur] + off);
      }
#pragma unroll
      for (int mf = 0; mf < 4; ++mf)
#pragma unroll
        for (int nf = 0; nf < 4; ++nf)
          acc[mf][nf] = __builtin_amdgcn_mfma_f32_16x16x32_bf16(af[mf], bfr[kk * 4 + nf], acc[mf][nf], 0, 0, 0);
    }

    if (ks < 7) {
      lwriteA(cur ^ 1);              // waits vmcnt on A regs, publishes tile
      __syncthreads();
      cur ^= 1;
    }
  }

  // ---- epilogue: bias + store ----
  float bs[4];
#pragma unroll
  for (int nf = 0; nf < 4; ++nf)
    bs[nf] = bias[bn * 128 + wc * 64 + nf * 16 + lrow];

  const int r0 = (lane >> 4) * 4;
#pragma unroll
  for (int mf = 0; mf < 4; ++mf) {
#pragma unroll
    for (int nf = 0; nf < 4; ++nf) {
      int gcol = bn * 128 + wc * 64 + nf * 16 + lrow;
#pragma unroll
      for (int r = 0; r < 4; ++r) {
        int grow = bm * 128 + wr * 64 + mf * 16 + r0 + r;
        float val = acc[mf][nf][r] + bs[nf];
        if (OUT_F32) ((float*)Cp)[(size_t)grow * 512 + gcol] = val;
        else         ((ushort*)Cp)[(size_t)grow * 512 + gcol] = f2b(val);
      }
    }
  }
}

// ---------------------------------------------------------------------------
// Attention: one block per (b,t). k/v rows for this t staged in LDS.
// ---------------------------------------------------------------------------
__global__ __launch_bounds__(256, 2)
void attn_kernel(const ushort* __restrict__ q, const ushort* __restrict__ k,
                 const ushort* __restrict__ v, const int* __restrict__ mask,
                 ushort* __restrict__ x, int bt0)
{
  __shared__ ushort lk[W_][520];
  __shared__ ushort lv[W_][520];
  __shared__ ushort lq[512];
  __shared__ float  sc[H_][W_];
  __shared__ float  aw[H_][W_];
  __shared__ float  mx[H_], inv[H_];
  __shared__ int    msk[W_];

  const int tid = threadIdx.x;
  const int bt  = blockIdx.x + bt0;        // global b*T + t

  if (tid < 64) ((short8*)lq)[tid] = ((const short8*)(q + (size_t)bt * 512))[tid];
  if (tid < W_) msk[tid] = mask[(size_t)bt * W_ + tid];

  size_t kvbase = (size_t)blockIdx.x * (W_ * 512);
  for (int c = tid; c < W_ * 64; c += 256) {
    int w  = c >> 6;
    int d8 = (c & 63) * 8;
    *(short8*)&lk[w][d8] = *(const short8*)(k + kvbase + w * 512 + d8);
    *(short8*)&lv[w][d8] = *(const short8*)(v + kvbase + w * 512 + d8);
  }
  __syncthreads();

  for (int task = tid; task < H_ * W_; task += 256) {
    int h = task / W_, w = task % W_;
    const ushort* kr = &lk[w][h * 64];
    const ushort* qr = &lq[h * 64];
    float s = 0.f;
#pragma unroll
    for (int d8 = 0; d8 < 8; ++d8) {
      short8 qv = *(const short8*)(qr + d8 * 8);
      short8 kv = *(const short8*)(kr + d8 * 8);
#pragma unroll
      for (int j = 0; j < 8; ++j) s += b2f((ushort)qv[j]) * b2f((ushort)kv[j]);
    }
    s *= 0.125f;
    sc[h][w] = msk[w] ? s : -3.4028234663852886e38f;
  }
  __syncthreads();

  if (tid < H_) {
    float m = -3.4028234663852886e38f;
    for (int w = 0; w < W_; ++w) m = fmaxf(m, sc[tid][w]);
    float ssum = 0.f;
    for (int w = 0; w < W_; ++w) ssum += __expf(sc[tid][w] - m);
    mx[tid] = m;
    inv[tid] = 1.f / ssum;
  }
  __syncthreads();

  for (int task = tid; task < H_ * W_; task += 256) {
    int h = task / W_, w = task % W_;
    aw[h][w] = msk[w] ? __expf(sc[h][w] - mx[h]) * inv[h] : 0.f;
  }
  __syncthreads();

  for (int f = tid; f < 512; f += 256) {
    int h = f >> 6, d = f & 63;
    float a = 0.f;
#pragma unroll
    for (int w = 0; w < W_; ++w) a += aw[h][w] * b2f(lv[w][h * 64 + d]);
    x[(size_t)bt * 512 + f] = f2b(a);
  }
}

// ---------------------------------------------------------------------------
extern "C" void kernel_launch(void* const* d_in, const int* in_sizes, int n_in,
                              void* d_out, int out_size, void* d_ws, size_t ws_size,
                              hipStream_t stream)
{
  const float* query = (const float*)d_in[0];
  const float* key   = (const float*)d_in[1];
  const float* value = (const float*)d_in[2];
  const int*   mask  = (const int*)d_in[3];
  const float* Wq    = (const float*)d_in[4];
  const float* bq    = (const float*)d_in[5];
  const float* Wk    = (const float*)d_in[6];
  const float* bk    = (const float*)d_in[7];
  const float* Wv    = (const float*)d_in[8];
  const float* bv    = (const float*)d_in[9];
  const float* Wo    = (const float*)d_in[10];
  const float* bo    = (const float*)d_in[11];

  char* ws = (char*)d_ws;
  ushort* Wt   = (ushort*)ws;                         // 4 x 512x512 bf16 = 2 MB
  ushort* Wtq  = Wt;
  ushort* Wtk  = Wt + 262144;
  ushort* Wtv  = Wt + 524288;
  ushort* Wto  = Wt + 786432;
  ushort* qws  = (ushort*)(ws + 2 * 1024 * 1024);     // 4 MB
  ushort* xws  = (ushort*)(ws + 6 * 1024 * 1024);     // 4 MB
  ushort* kvws = (ushort*)(ws + 10 * 1024 * 1024);

  // chunk the (b*T) dimension so k/v bf16 intermediates fit in ws
  size_t fixed = 10ull * 1024 * 1024;
  size_t avail = ws_size > fixed ? ws_size - fixed : 0;
  long trl = (long)(avail / (2ull * W_ * 512 * 2));   // t-rows that fit
  int TR = (int)(trl / 128) * 128;
  if (TR > B_ * T_) TR = B_ * T_;
  if (TR < 128) TR = 128;
  ushort* kws = kvws;
  ushort* vws = kvws + (size_t)TR * W_ * 512;

  convert_w<<<dim3(1024, 4), 256, 0, stream>>>(Wq, Wk, Wv, Wo, Wt);

  // Q projection: M=4096 -> 32 M-tiles
  gemm_kernel<true, false><<<dim3(128, 1), 256, 0, stream>>>(
      query, query, Wtq, Wtq, bq, bq, qws, qws, 1);

  for (int bt0 = 0; bt0 < B_ * T_; bt0 += TR) {
    int rows = B_ * T_ - bt0; if (rows > TR) rows = TR;
    int Mt = rows * W_ / 128;              // rows is a multiple of 128
    int sw = (Mt % 8 == 0) ? 1 : 0;
    const float* kptr = key   + (size_t)bt0 * W_ * 512;
    const float* vptr = value + (size_t)bt0 * W_ * 512;
    // K-proj and V-proj merged into one dispatch (blockIdx.y selects)
    gemm_kernel<true, false><<<dim3(Mt * 4, 2), 256, 0, stream>>>(
        kptr, vptr, Wtk, Wtv, bk, bv, kws, vws, sw);
    attn_kernel<<<rows, 256, 0, stream>>>(qws, kws, vws, mask, xws, bt0);
  }

  // output projection: x @ Wo + bo -> f32 d_out
  gemm_kernel<false, true><<<dim3(128, 1), 256, 0, stream>>>(
      xws, xws, Wto, Wto, bo, bo, d_out, d_out, 1);
}